// Round 16
// baseline (2245.960 us; speedup 1.0000x reference)
//
#include <hip/hip_runtime.h>
#include <hip/hip_fp16.h>

#define N_NODES 1000000
#define N_EDGES 4000000
#define N_GRAPHS 32768
#define BN_EPS 1e-5f
#define NBLK1 3907   // ceil(N_NODES/256)

typedef _Float16 f16;
typedef f16   f16x8 __attribute__((ext_vector_type(8)));
typedef float f32x4 __attribute__((ext_vector_type(4)));

// ---------------------------------------------------------------------------
// Static device-global scratch (ws_size too small for the intermediates).
// fp16 ping-pong feature buffers keep the edge-gather set L3-resident.
// NOTE: device globals must ONLY be referenced from device code (round-6
// fault: host-side refs pass the host shadow address). Buffer selection is
// via template parameters.
// ---------------------------------------------------------------------------
__device__ __half g_hA[128000000];      // 256 MB node features
__device__ __half g_hB[128000000];      // 256 MB node features (aliased as f32 px in layer 1)
__device__ float  g_agg7[7000000];      //  28 MB layer-1 agg; later pooled+hidden
__device__ float  g_dinv[N_NODES];
__device__ int    g_rowcnt[N_NODES];
__device__ int    g_row_start[N_NODES + 1];
__device__ int    g_csr_src[N_EDGES];
__device__ int    g_part[NBLK1];
__device__ int    g_gstart[N_GRAPHS + 1];
__device__ __align__(16) __half g_wt2[16384];   // W2^T fp16 [n][k]
__device__ __align__(16) __half g_wt3[16384];   // W3^T fp16 [n][k]

#define HIDDEN_OFF 4259840   // pooled = g_agg7[0..4194304); hidden after pad

// ---------------- fp16 helpers (16 B = 8 halfs per lane) ----------------

__device__ __forceinline__ void set8(uint4 raw, float f[8]) {
    __half2 h; float2 a;
    __builtin_memcpy(&h, &raw.x, 4); a = __half22float2(h); f[0] = a.x; f[1] = a.y;
    __builtin_memcpy(&h, &raw.y, 4); a = __half22float2(h); f[2] = a.x; f[3] = a.y;
    __builtin_memcpy(&h, &raw.z, 4); a = __half22float2(h); f[4] = a.x; f[5] = a.y;
    __builtin_memcpy(&h, &raw.w, 4); a = __half22float2(h); f[6] = a.x; f[7] = a.y;
}
__device__ __forceinline__ void add8(uint4 raw, float f[8]) {
    __half2 h; float2 a;
    __builtin_memcpy(&h, &raw.x, 4); a = __half22float2(h); f[0] += a.x; f[1] += a.y;
    __builtin_memcpy(&h, &raw.y, 4); a = __half22float2(h); f[2] += a.x; f[3] += a.y;
    __builtin_memcpy(&h, &raw.z, 4); a = __half22float2(h); f[4] += a.x; f[5] += a.y;
    __builtin_memcpy(&h, &raw.w, 4); a = __half22float2(h); f[6] += a.x; f[7] += a.y;
}
__device__ __forceinline__ uint4 pack8(const float f[8]) {
    __half2 h0 = __floats2half2_rn(f[0], f[1]);
    __half2 h1 = __floats2half2_rn(f[2], f[3]);
    __half2 h2 = __floats2half2_rn(f[4], f[5]);
    __half2 h3 = __floats2half2_rn(f[6], f[7]);
    uint4 raw;
    __builtin_memcpy(&raw.x, &h0, 4);
    __builtin_memcpy(&raw.y, &h1, 4);
    __builtin_memcpy(&raw.z, &h2, 4);
    __builtin_memcpy(&raw.w, &h3, 4);
    return raw;
}

// ---------------- CSR build ----------------

__global__ __launch_bounds__(256) void k_zero_cnt() {
    int i = blockIdx.x * 256 + threadIdx.x;
    if (i < N_NODES) g_rowcnt[i] = 0;
}

__global__ __launch_bounds__(256) void k_hist(const int* __restrict__ dst) {
    int e = blockIdx.x * 256 + threadIdx.x;
    if (e < N_EDGES) atomicAdd(&g_rowcnt[dst[e]], 1);
}

__global__ __launch_bounds__(256) void k_dinv() {
    int i = blockIdx.x * 256 + threadIdx.x;
    if (i < N_NODES) g_dinv[i] = rsqrtf((float)(1 + g_rowcnt[i]));
}

__global__ __launch_bounds__(256) void k_scan1() {
    __shared__ int sh[256];
    int i = blockIdx.x * 256 + threadIdx.x;
    int v = (i < N_NODES) ? g_rowcnt[i] : 0;
    sh[threadIdx.x] = v;
    __syncthreads();
#pragma unroll
    for (int off = 1; off < 256; off <<= 1) {
        int t = (threadIdx.x >= off) ? sh[threadIdx.x - off] : 0;
        __syncthreads();
        sh[threadIdx.x] += t;
        __syncthreads();
    }
    int incl = sh[threadIdx.x];
    if (i < N_NODES) g_row_start[i] = incl - v;
    if (threadIdx.x == 255) g_part[blockIdx.x] = incl;
}

__global__ __launch_bounds__(256) void k_scan2() {
    __shared__ int sh[256];
    int base = threadIdx.x * 16;
    int local[16];
    int s = 0;
#pragma unroll
    for (int k = 0; k < 16; ++k) {
        local[k] = (base + k < NBLK1) ? g_part[base + k] : 0;
        s += local[k];
    }
    sh[threadIdx.x] = s;
    __syncthreads();
#pragma unroll
    for (int off = 1; off < 256; off <<= 1) {
        int t = (threadIdx.x >= off) ? sh[threadIdx.x - off] : 0;
        __syncthreads();
        sh[threadIdx.x] += t;
        __syncthreads();
    }
    int carry = sh[threadIdx.x] - s;
#pragma unroll
    for (int k = 0; k < 16; ++k) {
        if (base + k < NBLK1) {
            int t = local[k];
            g_part[base + k] = carry;
            carry += t;
        }
    }
}

__global__ __launch_bounds__(256) void k_scan3() {
    int i = blockIdx.x * 256 + threadIdx.x;
    if (i < N_NODES) {
        g_row_start[i] += g_part[blockIdx.x];
        g_rowcnt[i] = 0;
    }
    if (i == 0) g_row_start[N_NODES] = N_EDGES;
}

__global__ __launch_bounds__(256) void k_scatter(const int* __restrict__ src,
                                                 const int* __restrict__ dst) {
    int e = blockIdx.x * 256 + threadIdx.x;
    if (e >= N_EDGES) return;
    int d = dst[e];
    int pos = g_row_start[d] + atomicAdd(&g_rowcnt[d], 1);
    g_csr_src[pos] = src[e];
}

// ---------------- W transpose to fp16 (per layer) ----------------
// Wt[n][k] = (fp16) W[k][n]; coalesced read, scattered 2B write (32 KB total).

template <int SEL>
__global__ __launch_bounds__(256) void k_wt(const float* __restrict__ W) {
    __half* dst = (SEL == 0) ? g_wt2 : g_wt3;
    int t = blockIdx.x * 256 + threadIdx.x;   // 0..16383
    int n = t & 127, k = t >> 7;
    dst[n * 128 + k] = __float2half_rn(W[k * 128 + n]);
}

// ---------------- layer 1 ----------------

// px[i] = dinv[i]*x[i]  (px aliases g_hB as f32; dead once layer 2 runs)
__global__ __launch_bounds__(256) void k_p7(const float* __restrict__ x) {
    int i = blockIdx.x * 256 + threadIdx.x;
    if (i >= N_NODES) return;
    float w = g_dinv[i];
    float* px = (float*)g_hB;
#pragma unroll
    for (int k = 0; k < 7; ++k) px[i * 7 + k] = x[i * 7 + k] * w;
}

// agg7[d] = px[d] + sum px[s], 8 lanes/node, 4-deep MLP
__global__ __launch_bounds__(256) void k_agg7_csr() {
    int t = blockIdx.x * 256 + threadIdx.x;
    int i = t >> 3;
    int c = t & 7;
    if (i >= N_NODES || c >= 7) return;
    const float* px = (const float*)g_hB;
    float acc = px[i * 7 + c];
    int e = g_row_start[i], e1 = g_row_start[i + 1];
    for (; e + 4 <= e1; e += 4) {
        int s0 = g_csr_src[e + 0], s1 = g_csr_src[e + 1];
        int s2 = g_csr_src[e + 2], s3 = g_csr_src[e + 3];
        float v0 = px[s0 * 7 + c], v1 = px[s1 * 7 + c];
        float v2 = px[s2 * 7 + c], v3 = px[s3 * 7 + c];
        acc += (v0 + v1) + (v2 + v3);
    }
    for (; e < e1; ++e) acc += px[g_csr_src[e] * 7 + c];
    g_agg7[i * 7 + c] = acc;
}

// h1 = relu(bn(dinv*(agg7.W1) + b)); store q1 = dinv*h1 (fp16, half2 stores)
__global__ __launch_bounds__(256) void k_lin1_bn_relu(const float* __restrict__ W,
                                                      const float* __restrict__ b,
                                                      const float* __restrict__ g,
                                                      const float* __restrict__ bt,
                                                      const float* __restrict__ rm,
                                                      const float* __restrict__ rv) {
    int t = blockIdx.x * 256 + threadIdx.x;   // node*64 + cpair
    int i = t >> 6, c = (t & 63) * 2;
    if (i >= N_NODES) return;
    float a[7];
#pragma unroll
    for (int k = 0; k < 7; ++k) a[k] = g_agg7[i * 7 + k];
    float z0 = 0.f, z1 = 0.f;
#pragma unroll
    for (int k = 0; k < 7; ++k) {
        z0 = fmaf(a[k], W[k * 128 + c], z0);
        z1 = fmaf(a[k], W[k * 128 + c + 1], z1);
    }
    float dv = g_dinv[i];
    z0 *= dv; z1 *= dv;
    float s0 = g[c] * rsqrtf(rv[c] + BN_EPS);
    float s1 = g[c + 1] * rsqrtf(rv[c + 1] + BN_EPS);
    float o0 = fmaf(b[c] - rm[c], s0, bt[c]);
    float o1 = fmaf(b[c + 1] - rm[c + 1], s1, bt[c + 1]);
    float h0 = fmaxf(fmaf(z0, s0, o0), 0.f) * dv;
    float h1 = fmaxf(fmaf(z1, s1, o1), 0.f) * dv;
    __half2 out = __floats2half2_rn(h0, h1);
    *(__half2*)(g_hA + (size_t)i * 128 + c) = out;
}

// ---------------- fused CSR-gather + MFMA GEMM + BN + ReLU ------------------
// 64 nodes/block, 256 threads (4 waves).
// Gather: 16 lanes/node x 8ch (16B fp16 loads), MLP-4, f32 acc -> fp16 As.
// GEMM: v_mfma_f32_16x16x32_f16, per wave 16 rows x 128 cols, K=128 in 4x32.
//   A-frag (m=lane&15, k=quad*8+j) from LDS As. B-frag (n=lane&15, same k)
//   loaded DIRECT FROM GLOBAL Wt (32 KB, identical addrs across all blocks ->
//   L1/L2 broadcast). ROUND-15 POST-MORTEM: the old LDS Wtc staging had 8-way
//   bank aliasing (1.4e7 SQ_LDS_BANK_CONFLICT) and forced 2 barriers per kb;
//   occupancy fell to 34%. Removing it: LDS = As only = 19,456 B (8 blocks/CU
//   by LDS), barriers 9 -> 2, conflicts gone. __launch_bounds__(256,6) caps
//   VGPR ~85 for 6 blocks/CU.
// No pre-epilogue barrier: wave wv's MFMA reads and epilogue writes touch only
// rows [m0, m0+16) and per-wave DS ops are in-order (WAR safe).
// C layout (HW-verified): col=lane&15, row=(lane>>4)*4+reg. C staged through
// As for coalesced 16B stores; store loop = 4 iters (64 rows x 128 cols).

template <bool PRE, bool ATOB, int WSEL>
__global__ __launch_bounds__(256, 6) void k_agg_gemm(const float* __restrict__ b,
                                                     const float* __restrict__ g,
                                                     const float* __restrict__ bt,
                                                     const float* __restrict__ rm,
                                                     const float* __restrict__ rv) {
    const __half* __restrict__ hin  = ATOB ? g_hA : g_hB;
    __half* __restrict__       hout = ATOB ? g_hB : g_hA;
    const __half* __restrict__ WtG  = (WSEL == 0) ? g_wt2 : g_wt3;

    __shared__ __half As[64][152];          // 19,456 B
    const int tid = threadIdx.x;
    const int node0 = blockIdx.x * 64;

    // ---- gather phase ----
    {
        const int slot = tid >> 4;          // 0..15
        const int c0 = (tid & 15) * 8;      // channel group (8 halfs = 16 B)
#pragma unroll
        for (int pass = 0; pass < 4; ++pass) {
            int i = node0 + pass * 16 + slot;
            float f[8];
            set8(*(const uint4*)(hin + (size_t)i * 128 + c0), f);   // self term
            int e = g_row_start[i], e1 = g_row_start[i + 1];
            for (; e + 4 <= e1; e += 4) {
                int s0 = g_csr_src[e + 0], s1 = g_csr_src[e + 1];
                int s2 = g_csr_src[e + 2], s3 = g_csr_src[e + 3];
                uint4 r0 = *(const uint4*)(hin + (size_t)s0 * 128 + c0);
                uint4 r1 = *(const uint4*)(hin + (size_t)s1 * 128 + c0);
                uint4 r2 = *(const uint4*)(hin + (size_t)s2 * 128 + c0);
                uint4 r3 = *(const uint4*)(hin + (size_t)s3 * 128 + c0);
                add8(r0, f); add8(r1, f); add8(r2, f); add8(r3, f);
            }
            for (; e < e1; ++e) {
                int s = g_csr_src[e];
                add8(*(const uint4*)(hin + (size_t)s * 128 + c0), f);
            }
            int row = pass * 16 + slot;
            *(uint4*)(&As[row][c0]) = pack8(f);
        }
    }
    __syncthreads();   // As visible to all waves

    // ---- MFMA GEMM phase (B direct from global; no barriers in loop) ----
    const int wv = tid >> 6;        // wave 0..3
    const int lane = tid & 63;
    const int lm = lane & 15;       // m (a-frag) / n (b-frag) / col (c-frag)
    const int lq = lane >> 4;       // quad
    const int m0 = wv * 16;

    f32x4 acc[8];
#pragma unroll
    for (int nt = 0; nt < 8; ++nt) acc[nt] = (f32x4){0.f, 0.f, 0.f, 0.f};

#pragma unroll
    for (int kb = 0; kb < 4; ++kb) {
        f16x8 afr;
        __builtin_memcpy(&afr, &As[m0 + lm][kb * 32 + lq * 8], 16);
#pragma unroll
        for (int nt = 0; nt < 8; ++nt) {
            f16x8 bfr;
            __builtin_memcpy(&bfr, WtG + (nt * 16 + lm) * 128 + kb * 32 + lq * 8, 16);
            acc[nt] = __builtin_amdgcn_mfma_f32_16x16x32_f16(afr, bfr, acc[nt], 0, 0, 0);
        }
    }

    // ---- epilogue: BN/ReLU, stage C in As (wave-local rows), store ----
    float4 dv4 = *(const float4*)(g_dinv + node0 + m0 + lq * 4);
    float dvr[4] = {dv4.x, dv4.y, dv4.z, dv4.w};

#pragma unroll
    for (int nt = 0; nt < 8; ++nt) {
        int c = nt * 16 + lm;
        float s = g[c] * rsqrtf(rv[c] + BN_EPS);
        float o = fmaf(b[c] - rm[c], s, bt[c]);
#pragma unroll
        for (int r = 0; r < 4; ++r) {
            float pm = PRE ? dvr[r] : 1.0f;
            float y = fmaxf(fmaf(acc[nt][r] * dvr[r], s, o), 0.f) * pm;
            As[m0 + lq * 4 + r][c] = __float2half_rn(y);
        }
    }
    __syncthreads();
#pragma unroll
    for (int i = 0; i < 4; ++i) {       // 1024 uint4 = 64 rows x 128 cols
        int u = tid + i * 256;          // 0..1023
        int row = u >> 4, cc = (u & 15) << 3;
        *(uint4*)(hout + (size_t)(node0 + row) * 128 + cc) = *(const uint4*)(&As[row][cc]);
    }
}

// ---------------- pooling + head ----------------

__global__ __launch_bounds__(256) void k_gstart(const int* __restrict__ batch) {
    int gidx = blockIdx.x * 256 + threadIdx.x;
    if (gidx > N_GRAPHS) return;
    int lo = 0, hi = N_NODES;
    while (lo < hi) {
        int mid = (lo + hi) >> 1;
        if (batch[mid] < gidx) lo = mid + 1; else hi = mid;
    }
    g_gstart[gidx] = lo;
}

__global__ __launch_bounds__(256) void k_pool_seg() {
    int t = blockIdx.x * 256 + threadIdx.x;
    int gi = t >> 4;
    if (gi >= N_GRAPHS) return;
    int c0 = (t & 15) * 8;
    int s0 = g_gstart[gi], s1 = g_gstart[gi + 1];
    float f[8] = {0.f, 0.f, 0.f, 0.f, 0.f, 0.f, 0.f, 0.f};
    for (int i = s0; i < s1; ++i)
        add8(*(const uint4*)(g_hA + (size_t)i * 128 + c0), f);
    float inv = 1.0f / (float)max(s1 - s0, 1);
    float* pooled = g_agg7;
    *(float4*)(pooled + (size_t)gi * 128 + c0)     = make_float4(f[0]*inv, f[1]*inv, f[2]*inv, f[3]*inv);
    *(float4*)(pooled + (size_t)gi * 128 + c0 + 4) = make_float4(f[4]*inv, f[5]*inv, f[6]*inv, f[7]*inv);
}

__global__ __launch_bounds__(256) void k_head1(const float* __restrict__ Wc1,
                                               const float* __restrict__ bc1) {
    int t = blockIdx.x * 256 + threadIdx.x;
    int gi = t >> 6, c = t & 63;
    if (gi >= N_GRAPHS) return;
    const float* pooled = g_agg7;
    float* hidden = g_agg7 + HIDDEN_OFF;
    float z = 0.f;
#pragma unroll 8
    for (int k = 0; k < 128; ++k) z = fmaf(pooled[gi * 128 + k], Wc1[k * 64 + c], z);
    hidden[t] = fmaxf(z + bc1[c], 0.f);
}

__global__ __launch_bounds__(256) void k_head2(const float* __restrict__ Wc2,
                                               const float* __restrict__ bc2,
                                               float* __restrict__ out) {
    int gi = blockIdx.x * 256 + threadIdx.x;
    if (gi >= N_GRAPHS) return;
    const float* hidden = g_agg7 + HIDDEN_OFF;
    float z = bc2[0];
#pragma unroll 8
    for (int k = 0; k < 64; ++k) z = fmaf(hidden[gi * 64 + k], Wc2[k], z);
    out[gi] = z;
}

// ---------------- launch ----------------

extern "C" void kernel_launch(void* const* d_in, const int* in_sizes, int n_in,
                              void* d_out, int out_size, void* d_ws, size_t ws_size,
                              hipStream_t stream) {
    const float* x     = (const float*)d_in[0];
    const int*   ei    = (const int*)d_in[1];
    const int*   batch = (const int*)d_in[2];
    const float* W1 = (const float*)d_in[3];
    const float* b1 = (const float*)d_in[4];
    const float* g1 = (const float*)d_in[5];
    const float* bt1= (const float*)d_in[6];
    const float* rm1= (const float*)d_in[7];
    const float* rv1= (const float*)d_in[8];
    const float* W2 = (const float*)d_in[9];
    const float* b2 = (const float*)d_in[10];
    const float* g2 = (const float*)d_in[11];
    const float* bt2= (const float*)d_in[12];
    const float* rm2= (const float*)d_in[13];
    const float* rv2= (const float*)d_in[14];
    const float* W3 = (const float*)d_in[15];
    const float* b3 = (const float*)d_in[16];
    const float* g3 = (const float*)d_in[17];
    const float* bt3= (const float*)d_in[18];
    const float* rm3= (const float*)d_in[19];
    const float* rv3= (const float*)d_in[20];
    const float* Wc1= (const float*)d_in[21];
    const float* bc1= (const float*)d_in[22];
    const float* Wc2= (const float*)d_in[23];
    const float* bc2= (const float*)d_in[24];
    float* outp = (float*)d_out;
    (void)d_ws; (void)ws_size; (void)n_in; (void)in_sizes;

    const int* srcp = ei;
    const int* dstp = ei + N_EDGES;

    // CSR build (by dst) + dinv
    k_zero_cnt<<<NBLK1, 256, 0, stream>>>();
    k_hist<<<(N_EDGES + 255) / 256, 256, 0, stream>>>(dstp);
    k_dinv<<<NBLK1, 256, 0, stream>>>();
    k_scan1<<<NBLK1, 256, 0, stream>>>();
    k_scan2<<<1, 256, 0, stream>>>();
    k_scan3<<<NBLK1, 256, 0, stream>>>();
    k_scatter<<<(N_EDGES + 255) / 256, 256, 0, stream>>>(srcp, dstp);

    // W2/W3 -> fp16 transposed (for MFMA B-fragments)
    k_wt<0><<<64, 256, 0, stream>>>(W2);
    k_wt<1><<<64, 256, 0, stream>>>(W3);

    // graph boundaries for pooling
    k_gstart<<<(N_GRAPHS + 1 + 255) / 256, 256, 0, stream>>>(batch);

    // layer 1: premultiply -> gather -> linear+BN+ReLU
    k_p7<<<(N_NODES + 255) / 256, 256, 0, stream>>>(x);
    k_agg7_csr<<<(N_NODES * 8) / 256, 256, 0, stream>>>();
    k_lin1_bn_relu<<<(N_NODES * 64) / 256, 256, 0, stream>>>(W1, b1, g1, bt1, rm1, rv1);

    // layers 2,3: fused gather + MFMA GEMM, ping-pong hA <-> hB
    k_agg_gemm<true,  true,  0><<<N_NODES / 64, 256, 0, stream>>>(b2, g2, bt2, rm2, rv2);
    k_agg_gemm<false, false, 1><<<N_NODES / 64, 256, 0, stream>>>(b3, g3, bt3, rm3, rv3);

    // segment-mean pool + head MLP
    k_pool_seg<<<(N_GRAPHS * 16) / 256, 256, 0, stream>>>();
    k_head1<<<(N_GRAPHS * 64) / 256, 256, 0, stream>>>(Wc1, bc1);
    k_head2<<<(N_GRAPHS + 255) / 256, 256, 0, stream>>>(Wc2, bc2, outp);
}

// Round 17
// 1879.366 us; speedup vs baseline: 1.1951x; 1.1951x over previous
//
#include <hip/hip_runtime.h>
#include <hip/hip_fp16.h>

#define N_NODES 1000000
#define N_EDGES 4000000
#define N_GRAPHS 32768
#define BN_EPS 1e-5f
#define NBLK1 3907   // ceil(N_NODES/256)

typedef _Float16 f16;
typedef f16   f16x8 __attribute__((ext_vector_type(8)));
typedef float f32x4 __attribute__((ext_vector_type(4)));

// ---------------------------------------------------------------------------
// Static device-global scratch (ws_size too small for the intermediates).
// fp16 ping-pong feature buffers keep the edge-gather set L3-resident.
// NOTE: device globals must ONLY be referenced from device code (round-6
// fault: host-side refs pass the host shadow address). Buffer selection is
// via template parameters.
// ---------------------------------------------------------------------------
__device__ __half g_hA[128000000];      // 256 MB node features
__device__ __half g_hB[128000000];      // 256 MB node features (aliased as f32 px in layer 1)
__device__ float  g_agg7[7000000];      //  28 MB layer-1 agg; later pooled+hidden
__device__ float  g_dinv[N_NODES];
__device__ int    g_rowcnt[N_NODES];
__device__ int    g_row_start[N_NODES + 1];
__device__ int    g_csr_src[N_EDGES];
__device__ int    g_part[NBLK1];
__device__ int    g_gstart[N_GRAPHS + 1];
__device__ __align__(16) __half g_wt2[16384];   // W2^T fp16 [n][k]
__device__ __align__(16) __half g_wt3[16384];   // W3^T fp16 [n][k]

#define HIDDEN_OFF 4259840   // pooled = g_agg7[0..4194304); hidden after pad

// ---------------- fp16 helpers (16 B = 8 halfs per lane) ----------------

__device__ __forceinline__ void set8(uint4 raw, float f[8]) {
    __half2 h; float2 a;
    __builtin_memcpy(&h, &raw.x, 4); a = __half22float2(h); f[0] = a.x; f[1] = a.y;
    __builtin_memcpy(&h, &raw.y, 4); a = __half22float2(h); f[2] = a.x; f[3] = a.y;
    __builtin_memcpy(&h, &raw.z, 4); a = __half22float2(h); f[4] = a.x; f[5] = a.y;
    __builtin_memcpy(&h, &raw.w, 4); a = __half22float2(h); f[6] = a.x; f[7] = a.y;
}
__device__ __forceinline__ void add8(uint4 raw, float f[8]) {
    __half2 h; float2 a;
    __builtin_memcpy(&h, &raw.x, 4); a = __half22float2(h); f[0] += a.x; f[1] += a.y;
    __builtin_memcpy(&h, &raw.y, 4); a = __half22float2(h); f[2] += a.x; f[3] += a.y;
    __builtin_memcpy(&h, &raw.z, 4); a = __half22float2(h); f[4] += a.x; f[5] += a.y;
    __builtin_memcpy(&h, &raw.w, 4); a = __half22float2(h); f[6] += a.x; f[7] += a.y;
}
__device__ __forceinline__ uint4 pack8(const float f[8]) {
    __half2 h0 = __floats2half2_rn(f[0], f[1]);
    __half2 h1 = __floats2half2_rn(f[2], f[3]);
    __half2 h2 = __floats2half2_rn(f[4], f[5]);
    __half2 h3 = __floats2half2_rn(f[6], f[7]);
    uint4 raw;
    __builtin_memcpy(&raw.x, &h0, 4);
    __builtin_memcpy(&raw.y, &h1, 4);
    __builtin_memcpy(&raw.z, &h2, 4);
    __builtin_memcpy(&raw.w, &h3, 4);
    return raw;
}

// ---------------- CSR build ----------------

__global__ __launch_bounds__(256) void k_zero_cnt() {
    int i = blockIdx.x * 256 + threadIdx.x;
    if (i < N_NODES) g_rowcnt[i] = 0;
}

__global__ __launch_bounds__(256) void k_hist(const int* __restrict__ dst) {
    int e = blockIdx.x * 256 + threadIdx.x;
    if (e < N_EDGES) atomicAdd(&g_rowcnt[dst[e]], 1);
}

// scan1 also computes dinv (reads rowcnt anyway) — saves a launch
__global__ __launch_bounds__(256) void k_scan1() {
    __shared__ int sh[256];
    int i = blockIdx.x * 256 + threadIdx.x;
    int v = (i < N_NODES) ? g_rowcnt[i] : 0;
    if (i < N_NODES) g_dinv[i] = rsqrtf((float)(1 + v));   // +1 self-loop
    sh[threadIdx.x] = v;
    __syncthreads();
#pragma unroll
    for (int off = 1; off < 256; off <<= 1) {
        int t = (threadIdx.x >= off) ? sh[threadIdx.x - off] : 0;
        __syncthreads();
        sh[threadIdx.x] += t;
        __syncthreads();
    }
    int incl = sh[threadIdx.x];
    if (i < N_NODES) g_row_start[i] = incl - v;
    if (threadIdx.x == 255) g_part[blockIdx.x] = incl;
}

__global__ __launch_bounds__(256) void k_scan2() {
    __shared__ int sh[256];
    int base = threadIdx.x * 16;
    int local[16];
    int s = 0;
#pragma unroll
    for (int k = 0; k < 16; ++k) {
        local[k] = (base + k < NBLK1) ? g_part[base + k] : 0;
        s += local[k];
    }
    sh[threadIdx.x] = s;
    __syncthreads();
#pragma unroll
    for (int off = 1; off < 256; off <<= 1) {
        int t = (threadIdx.x >= off) ? sh[threadIdx.x - off] : 0;
        __syncthreads();
        sh[threadIdx.x] += t;
        __syncthreads();
    }
    int carry = sh[threadIdx.x] - s;
#pragma unroll
    for (int k = 0; k < 16; ++k) {
        if (base + k < NBLK1) {
            int t = local[k];
            g_part[base + k] = carry;
            carry += t;
        }
    }
}

__global__ __launch_bounds__(256) void k_scan3() {
    int i = blockIdx.x * 256 + threadIdx.x;
    if (i < N_NODES) {
        g_row_start[i] += g_part[blockIdx.x];
        g_rowcnt[i] = 0;
    }
    if (i == 0) g_row_start[N_NODES] = N_EDGES;
}

__global__ __launch_bounds__(256) void k_scatter(const int* __restrict__ src,
                                                 const int* __restrict__ dst) {
    int e = blockIdx.x * 256 + threadIdx.x;
    if (e >= N_EDGES) return;
    int d = dst[e];
    int pos = g_row_start[d] + atomicAdd(&g_rowcnt[d], 1);
    g_csr_src[pos] = src[e];
}

// ---------------- W2+W3 transpose to fp16 (single launch) ----------------
// Wt[n][k] = (fp16) W[k][n]. Blocks 0..63 -> W2, 64..127 -> W3.

__global__ __launch_bounds__(256) void k_wt_both(const float* __restrict__ W2,
                                                 const float* __restrict__ W3) {
    int t = blockIdx.x * 256 + threadIdx.x;   // 0..32767
    int sel = t >> 14, u = t & 16383;
    int n = u & 127, k = u >> 7;
    __half* dst = sel ? g_wt3 : g_wt2;
    const float* W = sel ? W3 : W2;
    dst[n * 128 + k] = __float2half_rn(W[k * 128 + n]);
}

// ---------------- layer 1 ----------------

// px[i] = dinv[i]*x[i]  (px aliases g_hB as f32; dead once layer 2 runs)
__global__ __launch_bounds__(256) void k_p7(const float* __restrict__ x) {
    int i = blockIdx.x * 256 + threadIdx.x;
    if (i >= N_NODES) return;
    float w = g_dinv[i];
    float* px = (float*)g_hB;
#pragma unroll
    for (int k = 0; k < 7; ++k) px[i * 7 + k] = x[i * 7 + k] * w;
}

// agg7[d] = px[d] + sum px[s], 8 lanes/node, 4-deep MLP
__global__ __launch_bounds__(256) void k_agg7_csr() {
    int t = blockIdx.x * 256 + threadIdx.x;
    int i = t >> 3;
    int c = t & 7;
    if (i >= N_NODES || c >= 7) return;
    const float* px = (const float*)g_hB;
    float acc = px[i * 7 + c];
    int e = g_row_start[i], e1 = g_row_start[i + 1];
    for (; e + 4 <= e1; e += 4) {
        int s0 = g_csr_src[e + 0], s1 = g_csr_src[e + 1];
        int s2 = g_csr_src[e + 2], s3 = g_csr_src[e + 3];
        float v0 = px[s0 * 7 + c], v1 = px[s1 * 7 + c];
        float v2 = px[s2 * 7 + c], v3 = px[s3 * 7 + c];
        acc += (v0 + v1) + (v2 + v3);
    }
    for (; e < e1; ++e) acc += px[g_csr_src[e] * 7 + c];
    g_agg7[i * 7 + c] = acc;
}

// h1 = relu(bn(dinv*(agg7.W1) + b)); store q1 = dinv*h1 (fp16, half2 stores)
__global__ __launch_bounds__(256) void k_lin1_bn_relu(const float* __restrict__ W,
                                                      const float* __restrict__ b,
                                                      const float* __restrict__ g,
                                                      const float* __restrict__ bt,
                                                      const float* __restrict__ rm,
                                                      const float* __restrict__ rv) {
    int t = blockIdx.x * 256 + threadIdx.x;   // node*64 + cpair
    int i = t >> 6, c = (t & 63) * 2;
    if (i >= N_NODES) return;
    float a[7];
#pragma unroll
    for (int k = 0; k < 7; ++k) a[k] = g_agg7[i * 7 + k];
    float z0 = 0.f, z1 = 0.f;
#pragma unroll
    for (int k = 0; k < 7; ++k) {
        z0 = fmaf(a[k], W[k * 128 + c], z0);
        z1 = fmaf(a[k], W[k * 128 + c + 1], z1);
    }
    float dv = g_dinv[i];
    z0 *= dv; z1 *= dv;
    float s0 = g[c] * rsqrtf(rv[c] + BN_EPS);
    float s1 = g[c + 1] * rsqrtf(rv[c + 1] + BN_EPS);
    float o0 = fmaf(b[c] - rm[c], s0, bt[c]);
    float o1 = fmaf(b[c + 1] - rm[c + 1], s1, bt[c + 1]);
    float h0 = fmaxf(fmaf(z0, s0, o0), 0.f) * dv;
    float h1 = fmaxf(fmaf(z1, s1, o1), 0.f) * dv;
    __half2 out = __floats2half2_rn(h0, h1);
    *(__half2*)(g_hA + (size_t)i * 128 + c) = out;
}

// ---------------- fused CSR-gather + MFMA GEMM + BN + ReLU ------------------
// 64 nodes/block, 256 threads (4 waves).
// Gather: 16 lanes/node x 8ch (16B fp16 loads), MLP-4, f32 acc -> fp16 As.
// GEMM (ROUND-16 POST-MORTEM: per-kb global B-reads = 2 GB L1/L2 traffic,
// thrashed caches, +252 MB HBM FETCH): COLUMN-SPLIT waves — wave wv owns
// cols [wv*32, wv*32+32) x all 64 rows. B-fragments = 2 nt x 4 kb = 8 frags
// = 32 VGPRs, loaded from global ONCE per block (32 KB/block, 500 MB total),
// issued before the post-gather barrier so load latency hides under it.
// LDS = As only (19,456 B). A-frag: m=lane&15, k=quad*8+j from As (pad 152,
// 2-way free). C layout (HW-verified): col=lane&15, row=quad*4+reg.
// Pre-epilogue barrier required (every wave reads all As rows). Store loop =
// 4 iters (64 rows x 128 cols) — round-12 fix retained.

template <bool PRE, bool ATOB, int WSEL>
__global__ __launch_bounds__(256, 5) void k_agg_gemm(const float* __restrict__ b,
                                                     const float* __restrict__ g,
                                                     const float* __restrict__ bt,
                                                     const float* __restrict__ rm,
                                                     const float* __restrict__ rv) {
    const __half* __restrict__ hin  = ATOB ? g_hA : g_hB;
    __half* __restrict__       hout = ATOB ? g_hB : g_hA;
    const __half* __restrict__ WtG  = (WSEL == 0) ? g_wt2 : g_wt3;

    __shared__ __half As[64][152];          // 19,456 B
    const int tid = threadIdx.x;
    const int node0 = blockIdx.x * 64;

    // ---- gather phase ----
    {
        const int slot = tid >> 4;          // 0..15
        const int c0 = (tid & 15) * 8;      // channel group (8 halfs = 16 B)
#pragma unroll
        for (int pass = 0; pass < 4; ++pass) {
            int i = node0 + pass * 16 + slot;
            float f[8];
            set8(*(const uint4*)(hin + (size_t)i * 128 + c0), f);   // self term
            int e = g_row_start[i], e1 = g_row_start[i + 1];
            for (; e + 4 <= e1; e += 4) {
                int s0 = g_csr_src[e + 0], s1 = g_csr_src[e + 1];
                int s2 = g_csr_src[e + 2], s3 = g_csr_src[e + 3];
                uint4 r0 = *(const uint4*)(hin + (size_t)s0 * 128 + c0);
                uint4 r1 = *(const uint4*)(hin + (size_t)s1 * 128 + c0);
                uint4 r2 = *(const uint4*)(hin + (size_t)s2 * 128 + c0);
                uint4 r3 = *(const uint4*)(hin + (size_t)s3 * 128 + c0);
                add8(r0, f); add8(r1, f); add8(r2, f); add8(r3, f);
            }
            for (; e < e1; ++e) {
                int s = g_csr_src[e];
                add8(*(const uint4*)(hin + (size_t)s * 128 + c0), f);
            }
            int row = pass * 16 + slot;
            *(uint4*)(&As[row][c0]) = pack8(f);
        }
    }

    const int wv = tid >> 6;        // wave 0..3 -> cols [wv*32, wv*32+32)
    const int lane = tid & 63;
    const int lm = lane & 15;       // m (a-frag) / n (b-frag) / col (c-frag)
    const int lq = lane >> 4;       // quad

    // B-fragments for this wave's 2 n-tiles, loaded once (latency hides
    // under the barrier).
    f16x8 bfr[2][4];
#pragma unroll
    for (int nt = 0; nt < 2; ++nt)
#pragma unroll
        for (int kb = 0; kb < 4; ++kb)
            __builtin_memcpy(&bfr[nt][kb],
                             WtG + (size_t)(wv * 32 + nt * 16 + lm) * 128 + kb * 32 + lq * 8, 16);

    __syncthreads();   // As visible to all waves

    // ---- MFMA: 4 m-tiles x 4 kb x 2 nt ----
    f32x4 acc[4][2];
#pragma unroll
    for (int mt = 0; mt < 4; ++mt)
#pragma unroll
        for (int nt = 0; nt < 2; ++nt) acc[mt][nt] = (f32x4){0.f, 0.f, 0.f, 0.f};

#pragma unroll
    for (int mt = 0; mt < 4; ++mt) {
#pragma unroll
        for (int kb = 0; kb < 4; ++kb) {
            f16x8 afr;
            __builtin_memcpy(&afr, &As[mt * 16 + lm][kb * 32 + lq * 8], 16);
#pragma unroll
            for (int nt = 0; nt < 2; ++nt)
                acc[mt][nt] = __builtin_amdgcn_mfma_f32_16x16x32_f16(afr, bfr[nt][kb], acc[mt][nt], 0, 0, 0);
        }
    }

    // per-m-tile dinv rows
    float4 dv4[4];
#pragma unroll
    for (int mt = 0; mt < 4; ++mt)
        dv4[mt] = *(const float4*)(g_dinv + node0 + mt * 16 + lq * 4);

    __syncthreads();   // all As reads done before overwrite

    // ---- epilogue: BN/ReLU, stage C in As, coalesced store ----
#pragma unroll
    for (int nt = 0; nt < 2; ++nt) {
        int c = wv * 32 + nt * 16 + lm;
        float s = g[c] * rsqrtf(rv[c] + BN_EPS);
        float o = fmaf(b[c] - rm[c], s, bt[c]);
#pragma unroll
        for (int mt = 0; mt < 4; ++mt) {
            float dvr[4] = {dv4[mt].x, dv4[mt].y, dv4[mt].z, dv4[mt].w};
#pragma unroll
            for (int r = 0; r < 4; ++r) {
                float pm = PRE ? dvr[r] : 1.0f;
                float y = fmaxf(fmaf(acc[mt][nt][r] * dvr[r], s, o), 0.f) * pm;
                As[mt * 16 + lq * 4 + r][c] = __float2half_rn(y);
            }
        }
    }
    __syncthreads();
#pragma unroll
    for (int i = 0; i < 4; ++i) {       // 1024 uint4 = 64 rows x 128 cols
        int u = tid + i * 256;          // 0..1023
        int row = u >> 4, cc = (u & 15) << 3;
        *(uint4*)(hout + (size_t)(node0 + row) * 128 + cc) = *(const uint4*)(&As[row][cc]);
    }
}

// ---------------- pooling + head ----------------

__global__ __launch_bounds__(256) void k_gstart(const int* __restrict__ batch) {
    int gidx = blockIdx.x * 256 + threadIdx.x;
    if (gidx > N_GRAPHS) return;
    int lo = 0, hi = N_NODES;
    while (lo < hi) {
        int mid = (lo + hi) >> 1;
        if (batch[mid] < gidx) lo = mid + 1; else hi = mid;
    }
    g_gstart[gidx] = lo;
}

__global__ __launch_bounds__(256) void k_pool_seg() {
    int t = blockIdx.x * 256 + threadIdx.x;
    int gi = t >> 4;
    if (gi >= N_GRAPHS) return;
    int c0 = (t & 15) * 8;
    int s0 = g_gstart[gi], s1 = g_gstart[gi + 1];
    float f[8] = {0.f, 0.f, 0.f, 0.f, 0.f, 0.f, 0.f, 0.f};
    for (int i = s0; i < s1; ++i)
        add8(*(const uint4*)(g_hA + (size_t)i * 128 + c0), f);
    float inv = 1.0f / (float)max(s1 - s0, 1);
    float* pooled = g_agg7;
    *(float4*)(pooled + (size_t)gi * 128 + c0)     = make_float4(f[0]*inv, f[1]*inv, f[2]*inv, f[3]*inv);
    *(float4*)(pooled + (size_t)gi * 128 + c0 + 4) = make_float4(f[4]*inv, f[5]*inv, f[6]*inv, f[7]*inv);
}

__global__ __launch_bounds__(256) void k_head1(const float* __restrict__ Wc1,
                                               const float* __restrict__ bc1) {
    int t = blockIdx.x * 256 + threadIdx.x;
    int gi = t >> 6, c = t & 63;
    if (gi >= N_GRAPHS) return;
    const float* pooled = g_agg7;
    float* hidden = g_agg7 + HIDDEN_OFF;
    float z = 0.f;
#pragma unroll 8
    for (int k = 0; k < 128; ++k) z = fmaf(pooled[gi * 128 + k], Wc1[k * 64 + c], z);
    hidden[t] = fmaxf(z + bc1[c], 0.f);
}

__global__ __launch_bounds__(256) void k_head2(const float* __restrict__ Wc2,
                                               const float* __restrict__ bc2,
                                               float* __restrict__ out) {
    int gi = blockIdx.x * 256 + threadIdx.x;
    if (gi >= N_GRAPHS) return;
    const float* hidden = g_agg7 + HIDDEN_OFF;
    float z = bc2[0];
#pragma unroll 8
    for (int k = 0; k < 64; ++k) z = fmaf(hidden[gi * 64 + k], Wc2[k], z);
    out[gi] = z;
}

// ---------------- launch ----------------

extern "C" void kernel_launch(void* const* d_in, const int* in_sizes, int n_in,
                              void* d_out, int out_size, void* d_ws, size_t ws_size,
                              hipStream_t stream) {
    const float* x     = (const float*)d_in[0];
    const int*   ei    = (const int*)d_in[1];
    const int*   batch = (const int*)d_in[2];
    const float* W1 = (const float*)d_in[3];
    const float* b1 = (const float*)d_in[4];
    const float* g1 = (const float*)d_in[5];
    const float* bt1= (const float*)d_in[6];
    const float* rm1= (const float*)d_in[7];
    const float* rv1= (const float*)d_in[8];
    const float* W2 = (const float*)d_in[9];
    const float* b2 = (const float*)d_in[10];
    const float* g2 = (const float*)d_in[11];
    const float* bt2= (const float*)d_in[12];
    const float* rm2= (const float*)d_in[13];
    const float* rv2= (const float*)d_in[14];
    const float* W3 = (const float*)d_in[15];
    const float* b3 = (const float*)d_in[16];
    const float* g3 = (const float*)d_in[17];
    const float* bt3= (const float*)d_in[18];
    const float* rm3= (const float*)d_in[19];
    const float* rv3= (const float*)d_in[20];
    const float* Wc1= (const float*)d_in[21];
    const float* bc1= (const float*)d_in[22];
    const float* Wc2= (const float*)d_in[23];
    const float* bc2= (const float*)d_in[24];
    float* outp = (float*)d_out;
    (void)d_ws; (void)ws_size; (void)n_in; (void)in_sizes;

    const int* srcp = ei;
    const int* dstp = ei + N_EDGES;

    // CSR build (by dst) + dinv (fused into scan1)
    k_zero_cnt<<<NBLK1, 256, 0, stream>>>();
    k_hist<<<(N_EDGES + 255) / 256, 256, 0, stream>>>(dstp);
    k_scan1<<<NBLK1, 256, 0, stream>>>();
    k_scan2<<<1, 256, 0, stream>>>();
    k_scan3<<<NBLK1, 256, 0, stream>>>();
    k_scatter<<<(N_EDGES + 255) / 256, 256, 0, stream>>>(srcp, dstp);

    // W2+W3 -> fp16 transposed (single launch)
    k_wt_both<<<128, 256, 0, stream>>>(W2, W3);

    // graph boundaries for pooling
    k_gstart<<<(N_GRAPHS + 1 + 255) / 256, 256, 0, stream>>>(batch);

    // layer 1: premultiply -> gather -> linear+BN+ReLU
    k_p7<<<(N_NODES + 255) / 256, 256, 0, stream>>>(x);
    k_agg7_csr<<<(N_NODES * 8) / 256, 256, 0, stream>>>();
    k_lin1_bn_relu<<<(N_NODES * 64) / 256, 256, 0, stream>>>(W1, b1, g1, bt1, rm1, rv1);

    // layers 2,3: fused gather + MFMA GEMM, ping-pong hA <-> hB
    k_agg_gemm<true,  true,  0><<<N_NODES / 64, 256, 0, stream>>>(b2, g2, bt2, rm2, rv2);
    k_agg_gemm<false, false, 1><<<N_NODES / 64, 256, 0, stream>>>(b3, g3, bt3, rm3, rv3);

    // segment-mean pool + head MLP
    k_pool_seg<<<(N_GRAPHS * 16) / 256, 256, 0, stream>>>();
    k_head1<<<(N_GRAPHS * 64) / 256, 256, 0, stream>>>(Wc1, bc1);
    k_head2<<<(N_GRAPHS + 255) / 256, 256, 0, stream>>>(Wc2, bc2, outp);
}

// Round 18
// 1570.938 us; speedup vs baseline: 1.4297x; 1.1963x over previous
//
#include <hip/hip_runtime.h>
#include <hip/hip_fp16.h>

#define N_NODES 1000000
#define N_EDGES 4000000
#define N_GRAPHS 32768
#define BN_EPS 1e-5f
#define NBLK1 3907   // ceil(N_NODES/256)

typedef _Float16 f16;
typedef f16   f16x8 __attribute__((ext_vector_type(8)));
typedef float f32x4 __attribute__((ext_vector_type(4)));

// ---------------------------------------------------------------------------
// Static device-global scratch (ws_size too small for the intermediates).
// fp16 ping-pong feature buffers keep the edge-gather set L3-resident.
// NOTE: device globals must ONLY be referenced from device code (round-6
// fault: host-side refs pass the host shadow address). Buffer selection is
// via template parameters.
// ---------------------------------------------------------------------------
__device__ __half g_hA[128000000];      // 256 MB node features
__device__ __half g_hB[128000000];      // 256 MB node features (aliased as f32 px in layer 1)
__device__ float  g_agg7[8400000];      //  33.6 MB layer-1 agg (8 floats/node, padded); later pooled+hidden
__device__ float  g_dinv[N_NODES];
__device__ int    g_rowcnt[N_NODES];
__device__ int    g_row_start[N_NODES + 1];
__device__ int    g_csr_src[N_EDGES];
__device__ int    g_part[NBLK1];
__device__ int    g_gstart[N_GRAPHS + 1];
__device__ __align__(16) __half g_wt2[16384];   // W2^T fp16 [n][k]
__device__ __align__(16) __half g_wt3[16384];   // W3^T fp16 [n][k]

#define HIDDEN_OFF 4259840   // pooled = g_agg7[0..4194304); hidden after pad

// ---------------- fp16 helpers (16 B = 8 halfs per lane) ----------------

__device__ __forceinline__ void set8(uint4 raw, float f[8]) {
    __half2 h; float2 a;
    __builtin_memcpy(&h, &raw.x, 4); a = __half22float2(h); f[0] = a.x; f[1] = a.y;
    __builtin_memcpy(&h, &raw.y, 4); a = __half22float2(h); f[2] = a.x; f[3] = a.y;
    __builtin_memcpy(&h, &raw.z, 4); a = __half22float2(h); f[4] = a.x; f[5] = a.y;
    __builtin_memcpy(&h, &raw.w, 4); a = __half22float2(h); f[6] = a.x; f[7] = a.y;
}
__device__ __forceinline__ void add8(uint4 raw, float f[8]) {
    __half2 h; float2 a;
    __builtin_memcpy(&h, &raw.x, 4); a = __half22float2(h); f[0] += a.x; f[1] += a.y;
    __builtin_memcpy(&h, &raw.y, 4); a = __half22float2(h); f[2] += a.x; f[3] += a.y;
    __builtin_memcpy(&h, &raw.z, 4); a = __half22float2(h); f[4] += a.x; f[5] += a.y;
    __builtin_memcpy(&h, &raw.w, 4); a = __half22float2(h); f[6] += a.x; f[7] += a.y;
}
__device__ __forceinline__ uint4 pack8(const float f[8]) {
    __half2 h0 = __floats2half2_rn(f[0], f[1]);
    __half2 h1 = __floats2half2_rn(f[2], f[3]);
    __half2 h2 = __floats2half2_rn(f[4], f[5]);
    __half2 h3 = __floats2half2_rn(f[6], f[7]);
    uint4 raw;
    __builtin_memcpy(&raw.x, &h0, 4);
    __builtin_memcpy(&raw.y, &h1, 4);
    __builtin_memcpy(&raw.z, &h2, 4);
    __builtin_memcpy(&raw.w, &h3, 4);
    return raw;
}

// ---------------- CSR build ----------------

__global__ __launch_bounds__(256) void k_zero_cnt() {
    int i = blockIdx.x * 256 + threadIdx.x;
    if (i < N_NODES) g_rowcnt[i] = 0;
}

__global__ __launch_bounds__(256) void k_hist(const int* __restrict__ dst) {
    int e = blockIdx.x * 256 + threadIdx.x;
    if (e < N_EDGES) atomicAdd(&g_rowcnt[dst[e]], 1);
}

// scan1 also computes dinv (reads rowcnt anyway) — saves a launch
__global__ __launch_bounds__(256) void k_scan1() {
    __shared__ int sh[256];
    int i = blockIdx.x * 256 + threadIdx.x;
    int v = (i < N_NODES) ? g_rowcnt[i] : 0;
    if (i < N_NODES) g_dinv[i] = rsqrtf((float)(1 + v));   // +1 self-loop
    sh[threadIdx.x] = v;
    __syncthreads();
#pragma unroll
    for (int off = 1; off < 256; off <<= 1) {
        int t = (threadIdx.x >= off) ? sh[threadIdx.x - off] : 0;
        __syncthreads();
        sh[threadIdx.x] += t;
        __syncthreads();
    }
    int incl = sh[threadIdx.x];
    if (i < N_NODES) g_row_start[i] = incl - v;
    if (threadIdx.x == 255) g_part[blockIdx.x] = incl;
}

__global__ __launch_bounds__(256) void k_scan2() {
    __shared__ int sh[256];
    int base = threadIdx.x * 16;
    int local[16];
    int s = 0;
#pragma unroll
    for (int k = 0; k < 16; ++k) {
        local[k] = (base + k < NBLK1) ? g_part[base + k] : 0;
        s += local[k];
    }
    sh[threadIdx.x] = s;
    __syncthreads();
#pragma unroll
    for (int off = 1; off < 256; off <<= 1) {
        int t = (threadIdx.x >= off) ? sh[threadIdx.x - off] : 0;
        __syncthreads();
        sh[threadIdx.x] += t;
        __syncthreads();
    }
    int carry = sh[threadIdx.x] - s;
#pragma unroll
    for (int k = 0; k < 16; ++k) {
        if (base + k < NBLK1) {
            int t = local[k];
            g_part[base + k] = carry;
            carry += t;
        }
    }
}

__global__ __launch_bounds__(256) void k_scan3() {
    int i = blockIdx.x * 256 + threadIdx.x;
    if (i < N_NODES) {
        g_row_start[i] += g_part[blockIdx.x];
        g_rowcnt[i] = 0;
    }
    if (i == 0) g_row_start[N_NODES] = N_EDGES;
}

__global__ __launch_bounds__(256) void k_scatter(const int* __restrict__ src,
                                                 const int* __restrict__ dst) {
    int e = blockIdx.x * 256 + threadIdx.x;
    if (e >= N_EDGES) return;
    int d = dst[e];
    int pos = g_row_start[d] + atomicAdd(&g_rowcnt[d], 1);
    g_csr_src[pos] = src[e];
}

// ---------------- W2+W3 transpose to fp16 (single launch) ----------------
// Wt[n][k] = (fp16) W[k][n]. Blocks 0..63 -> W2, 64..127 -> W3.

__global__ __launch_bounds__(256) void k_wt_both(const float* __restrict__ W2,
                                                 const float* __restrict__ W3) {
    int t = blockIdx.x * 256 + threadIdx.x;   // 0..32767
    int sel = t >> 14, u = t & 16383;
    int n = u & 127, k = u >> 7;
    __half* dst = sel ? g_wt3 : g_wt2;
    const float* W = sel ? W3 : W2;
    dst[n * 128 + k] = __float2half_rn(W[k * 128 + n]);
}

// ---------------- layer 1 ----------------

// px[i] = dinv[i]*x[i]  (px aliases g_hB as f32; dead once layer 2 runs)
__global__ __launch_bounds__(256) void k_p7(const float* __restrict__ x) {
    int i = blockIdx.x * 256 + threadIdx.x;
    if (i >= N_NODES) return;
    float w = g_dinv[i];
    float* px = (float*)g_hB;
#pragma unroll
    for (int k = 0; k < 7; ++k) px[i * 7 + k] = x[i * 7 + k] * w;
}

// agg7[d] = px[d] + sum px[s], 8 lanes/node, 4-deep MLP.
// Stored PADDED to 8 floats/node (c==7 writes 0) so lin1 loads aligned float4s.
__global__ __launch_bounds__(256) void k_agg7_csr() {
    int t = blockIdx.x * 256 + threadIdx.x;
    int i = t >> 3;
    int c = t & 7;
    if (i >= N_NODES) return;
    if (c == 7) { g_agg7[(size_t)i * 8 + 7] = 0.f; return; }
    const float* px = (const float*)g_hB;
    float acc = px[i * 7 + c];
    int e = g_row_start[i], e1 = g_row_start[i + 1];
    for (; e + 4 <= e1; e += 4) {
        int s0 = g_csr_src[e + 0], s1 = g_csr_src[e + 1];
        int s2 = g_csr_src[e + 2], s3 = g_csr_src[e + 3];
        float v0 = px[s0 * 7 + c], v1 = px[s1 * 7 + c];
        float v2 = px[s2 * 7 + c], v3 = px[s3 * 7 + c];
        acc += (v0 + v1) + (v2 + v3);
    }
    for (; e < e1; ++e) acc += px[g_csr_src[e] * 7 + c];
    g_agg7[(size_t)i * 8 + c] = acc;
}

// h1 = relu(bn(dinv*(agg7.W1) + b)); store q1 = dinv*h1 (fp16).
// ROUND-17 POST-MORTEM: old mapping put ONE NODE PER WAVE (i = t>>6) — 7
// wave-uniform scalar-path loads + a single 4B/lane store per wave; 1M waves
// at ~1076 cyc/wave issue budget = 438 µs, latency/overhead-bound (hbm 8.5%,
// VALU 23%, occ 88%). New mapping: 16 threads/node x 8 ch, aligned 2xfloat4
// agg7 loads, W1+BN params staged in LDS, one uint4 fp16 store/thread (wave
// writes 1 KB contiguous). 62.5k blocks.
__global__ __launch_bounds__(256) void k_lin1_bn_relu(const float* __restrict__ W,
                                                      const float* __restrict__ b,
                                                      const float* __restrict__ g,
                                                      const float* __restrict__ bt,
                                                      const float* __restrict__ rm,
                                                      const float* __restrict__ rv) {
    __shared__ float Wsh[7][128];
    __shared__ float sSh[128], oSh[128];
    for (int v = threadIdx.x; v < 896; v += 256) Wsh[v >> 7][v & 127] = W[v];
    if (threadIdx.x < 128) {
        int c = threadIdx.x;
        float s = g[c] * rsqrtf(rv[c] + BN_EPS);
        sSh[c] = s;
        oSh[c] = fmaf(b[c] - rm[c], s, bt[c]);
    }
    __syncthreads();

    int t = blockIdx.x * 256 + threadIdx.x;   // node*16 + cgroup
    int i = t >> 4, c0 = (t & 15) * 8;        // grid exact: no bounds check
    float4 a03 = *(const float4*)(g_agg7 + (size_t)i * 8);
    float4 a47 = *(const float4*)(g_agg7 + (size_t)i * 8 + 4);
    float a[7] = {a03.x, a03.y, a03.z, a03.w, a47.x, a47.y, a47.z};
    float dv = g_dinv[i];
    float4 s04 = *(const float4*)(sSh + c0), s48 = *(const float4*)(sSh + c0 + 4);
    float4 o04 = *(const float4*)(oSh + c0), o48 = *(const float4*)(oSh + c0 + 4);
    float ss[8] = {s04.x, s04.y, s04.z, s04.w, s48.x, s48.y, s48.z, s48.w};
    float oo[8] = {o04.x, o04.y, o04.z, o04.w, o48.x, o48.y, o48.z, o48.w};
    float y[8];
#pragma unroll
    for (int j = 0; j < 8; ++j) {
        float z = 0.f;
#pragma unroll
        for (int k = 0; k < 7; ++k) z = fmaf(a[k], Wsh[k][c0 + j], z);
        z *= dv;
        y[j] = fmaxf(fmaf(z, ss[j], oo[j]), 0.f) * dv;   // premultiplied storage
    }
    *(uint4*)(g_hA + (size_t)i * 128 + c0) = pack8(y);
}

// ---------------- fused CSR-gather + MFMA GEMM + BN + ReLU ------------------
// 64 nodes/block, 256 threads (4 waves).
// Gather: 16 lanes/node x 8ch (16B fp16 loads), MLP-4, f32 acc -> fp16 As.
// GEMM: COLUMN-SPLIT waves — wave wv owns cols [wv*32, wv*32+32) x all 64
// rows. B-fragments = 2 nt x 4 kb = 8 frags = 32 VGPRs, loaded from global
// ONCE per block (32 KB/block), issued before the post-gather barrier so
// load latency hides under it. LDS = As only (19,456 B). A-frag: m=lane&15,
// k=quad*8+j from As (pad 152, 2-way free). C layout (HW-verified):
// col=lane&15, row=quad*4+reg. Store loop = 4 iters (round-12 fix).

template <bool PRE, bool ATOB, int WSEL>
__global__ __launch_bounds__(256, 5) void k_agg_gemm(const float* __restrict__ b,
                                                     const float* __restrict__ g,
                                                     const float* __restrict__ bt,
                                                     const float* __restrict__ rm,
                                                     const float* __restrict__ rv) {
    const __half* __restrict__ hin  = ATOB ? g_hA : g_hB;
    __half* __restrict__       hout = ATOB ? g_hB : g_hA;
    const __half* __restrict__ WtG  = (WSEL == 0) ? g_wt2 : g_wt3;

    __shared__ __half As[64][152];          // 19,456 B
    const int tid = threadIdx.x;
    const int node0 = blockIdx.x * 64;

    // ---- gather phase ----
    {
        const int slot = tid >> 4;          // 0..15
        const int c0 = (tid & 15) * 8;      // channel group (8 halfs = 16 B)
#pragma unroll
        for (int pass = 0; pass < 4; ++pass) {
            int i = node0 + pass * 16 + slot;
            float f[8];
            set8(*(const uint4*)(hin + (size_t)i * 128 + c0), f);   // self term
            int e = g_row_start[i], e1 = g_row_start[i + 1];
            for (; e + 4 <= e1; e += 4) {
                int s0 = g_csr_src[e + 0], s1 = g_csr_src[e + 1];
                int s2 = g_csr_src[e + 2], s3 = g_csr_src[e + 3];
                uint4 r0 = *(const uint4*)(hin + (size_t)s0 * 128 + c0);
                uint4 r1 = *(const uint4*)(hin + (size_t)s1 * 128 + c0);
                uint4 r2 = *(const uint4*)(hin + (size_t)s2 * 128 + c0);
                uint4 r3 = *(const uint4*)(hin + (size_t)s3 * 128 + c0);
                add8(r0, f); add8(r1, f); add8(r2, f); add8(r3, f);
            }
            for (; e < e1; ++e) {
                int s = g_csr_src[e];
                add8(*(const uint4*)(hin + (size_t)s * 128 + c0), f);
            }
            int row = pass * 16 + slot;
            *(uint4*)(&As[row][c0]) = pack8(f);
        }
    }

    const int wv = tid >> 6;        // wave 0..3 -> cols [wv*32, wv*32+32)
    const int lane = tid & 63;
    const int lm = lane & 15;       // m (a-frag) / n (b-frag) / col (c-frag)
    const int lq = lane >> 4;       // quad

    // B-fragments for this wave's 2 n-tiles, loaded once (latency hides
    // under the barrier).
    f16x8 bfr[2][4];
#pragma unroll
    for (int nt = 0; nt < 2; ++nt)
#pragma unroll
        for (int kb = 0; kb < 4; ++kb)
            __builtin_memcpy(&bfr[nt][kb],
                             WtG + (size_t)(wv * 32 + nt * 16 + lm) * 128 + kb * 32 + lq * 8, 16);

    __syncthreads();   // As visible to all waves

    // ---- MFMA: 4 m-tiles x 4 kb x 2 nt ----
    f32x4 acc[4][2];
#pragma unroll
    for (int mt = 0; mt < 4; ++mt)
#pragma unroll
        for (int nt = 0; nt < 2; ++nt) acc[mt][nt] = (f32x4){0.f, 0.f, 0.f, 0.f};

#pragma unroll
    for (int mt = 0; mt < 4; ++mt) {
#pragma unroll
        for (int kb = 0; kb < 4; ++kb) {
            f16x8 afr;
            __builtin_memcpy(&afr, &As[mt * 16 + lm][kb * 32 + lq * 8], 16);
#pragma unroll
            for (int nt = 0; nt < 2; ++nt)
                acc[mt][nt] = __builtin_amdgcn_mfma_f32_16x16x32_f16(afr, bfr[nt][kb], acc[mt][nt], 0, 0, 0);
        }
    }

    // per-m-tile dinv rows
    float4 dv4[4];
#pragma unroll
    for (int mt = 0; mt < 4; ++mt)
        dv4[mt] = *(const float4*)(g_dinv + node0 + mt * 16 + lq * 4);

    __syncthreads();   // all As reads done before overwrite

    // ---- epilogue: BN/ReLU, stage C in As, coalesced store ----
#pragma unroll
    for (int nt = 0; nt < 2; ++nt) {
        int c = wv * 32 + nt * 16 + lm;
        float s = g[c] * rsqrtf(rv[c] + BN_EPS);
        float o = fmaf(b[c] - rm[c], s, bt[c]);
#pragma unroll
        for (int mt = 0; mt < 4; ++mt) {
            float dvr[4] = {dv4[mt].x, dv4[mt].y, dv4[mt].z, dv4[mt].w};
#pragma unroll
            for (int r = 0; r < 4; ++r) {
                float pm = PRE ? dvr[r] : 1.0f;
                float y = fmaxf(fmaf(acc[mt][nt][r] * dvr[r], s, o), 0.f) * pm;
                As[mt * 16 + lq * 4 + r][c] = __float2half_rn(y);
            }
        }
    }
    __syncthreads();
#pragma unroll
    for (int i = 0; i < 4; ++i) {       // 1024 uint4 = 64 rows x 128 cols
        int u = tid + i * 256;          // 0..1023
        int row = u >> 4, cc = (u & 15) << 3;
        *(uint4*)(hout + (size_t)(node0 + row) * 128 + cc) = *(const uint4*)(&As[row][cc]);
    }
}

// ---------------- pooling + head ----------------

__global__ __launch_bounds__(256) void k_gstart(const int* __restrict__ batch) {
    int gidx = blockIdx.x * 256 + threadIdx.x;
    if (gidx > N_GRAPHS) return;
    int lo = 0, hi = N_NODES;
    while (lo < hi) {
        int mid = (lo + hi) >> 1;
        if (batch[mid] < gidx) lo = mid + 1; else hi = mid;
    }
    g_gstart[gidx] = lo;
}

__global__ __launch_bounds__(256) void k_pool_seg() {
    int t = blockIdx.x * 256 + threadIdx.x;
    int gi = t >> 4;
    if (gi >= N_GRAPHS) return;
    int c0 = (t & 15) * 8;
    int s0 = g_gstart[gi], s1 = g_gstart[gi + 1];
    float f[8] = {0.f, 0.f, 0.f, 0.f, 0.f, 0.f, 0.f, 0.f};
    for (int i = s0; i < s1; ++i)
        add8(*(const uint4*)(g_hA + (size_t)i * 128 + c0), f);
    float inv = 1.0f / (float)max(s1 - s0, 1);
    float* pooled = g_agg7;
    *(float4*)(pooled + (size_t)gi * 128 + c0)     = make_float4(f[0]*inv, f[1]*inv, f[2]*inv, f[3]*inv);
    *(float4*)(pooled + (size_t)gi * 128 + c0 + 4) = make_float4(f[4]*inv, f[5]*inv, f[6]*inv, f[7]*inv);
}

__global__ __launch_bounds__(256) void k_head1(const float* __restrict__ Wc1,
                                               const float* __restrict__ bc1) {
    int t = blockIdx.x * 256 + threadIdx.x;
    int gi = t >> 6, c = t & 63;
    if (gi >= N_GRAPHS) return;
    const float* pooled = g_agg7;
    float* hidden = g_agg7 + HIDDEN_OFF;
    float z = 0.f;
#pragma unroll 8
    for (int k = 0; k < 128; ++k) z = fmaf(pooled[gi * 128 + k], Wc1[k * 64 + c], z);
    hidden[t] = fmaxf(z + bc1[c], 0.f);
}

__global__ __launch_bounds__(256) void k_head2(const float* __restrict__ Wc2,
                                               const float* __restrict__ bc2,
                                               float* __restrict__ out) {
    int gi = blockIdx.x * 256 + threadIdx.x;
    if (gi >= N_GRAPHS) return;
    const float* hidden = g_agg7 + HIDDEN_OFF;
    float z = bc2[0];
#pragma unroll 8
    for (int k = 0; k < 64; ++k) z = fmaf(hidden[gi * 64 + k], Wc2[k], z);
    out[gi] = z;
}

// ---------------- launch ----------------

extern "C" void kernel_launch(void* const* d_in, const int* in_sizes, int n_in,
                              void* d_out, int out_size, void* d_ws, size_t ws_size,
                              hipStream_t stream) {
    const float* x     = (const float*)d_in[0];
    const int*   ei    = (const int*)d_in[1];
    const int*   batch = (const int*)d_in[2];
    const float* W1 = (const float*)d_in[3];
    const float* b1 = (const float*)d_in[4];
    const float* g1 = (const float*)d_in[5];
    const float* bt1= (const float*)d_in[6];
    const float* rm1= (const float*)d_in[7];
    const float* rv1= (const float*)d_in[8];
    const float* W2 = (const float*)d_in[9];
    const float* b2 = (const float*)d_in[10];
    const float* g2 = (const float*)d_in[11];
    const float* bt2= (const float*)d_in[12];
    const float* rm2= (const float*)d_in[13];
    const float* rv2= (const float*)d_in[14];
    const float* W3 = (const float*)d_in[15];
    const float* b3 = (const float*)d_in[16];
    const float* g3 = (const float*)d_in[17];
    const float* bt3= (const float*)d_in[18];
    const float* rm3= (const float*)d_in[19];
    const float* rv3= (const float*)d_in[20];
    const float* Wc1= (const float*)d_in[21];
    const float* bc1= (const float*)d_in[22];
    const float* Wc2= (const float*)d_in[23];
    const float* bc2= (const float*)d_in[24];
    float* outp = (float*)d_out;
    (void)d_ws; (void)ws_size; (void)n_in; (void)in_sizes;

    const int* srcp = ei;
    const int* dstp = ei + N_EDGES;

    // CSR build (by dst) + dinv (fused into scan1)
    k_zero_cnt<<<NBLK1, 256, 0, stream>>>();
    k_hist<<<(N_EDGES + 255) / 256, 256, 0, stream>>>(dstp);
    k_scan1<<<NBLK1, 256, 0, stream>>>();
    k_scan2<<<1, 256, 0, stream>>>();
    k_scan3<<<NBLK1, 256, 0, stream>>>();
    k_scatter<<<(N_EDGES + 255) / 256, 256, 0, stream>>>(srcp, dstp);

    // W2+W3 -> fp16 transposed (single launch)
    k_wt_both<<<128, 256, 0, stream>>>(W2, W3);

    // graph boundaries for pooling
    k_gstart<<<(N_GRAPHS + 1 + 255) / 256, 256, 0, stream>>>(batch);

    // layer 1: premultiply -> gather -> linear+BN+ReLU
    k_p7<<<(N_NODES + 255) / 256, 256, 0, stream>>>(x);
    k_agg7_csr<<<(N_NODES * 8) / 256, 256, 0, stream>>>();
    k_lin1_bn_relu<<<(N_NODES * 16) / 256, 256, 0, stream>>>(W1, b1, g1, bt1, rm1, rv1);

    // layers 2,3: fused gather + MFMA GEMM, ping-pong hA <-> hB
    k_agg_gemm<true,  true,  0><<<N_NODES / 64, 256, 0, stream>>>(b2, g2, bt2, rm2, rv2);
    k_agg_gemm<false, false, 1><<<N_NODES / 64, 256, 0, stream>>>(b3, g3, bt3, rm3, rv3);

    // segment-mean pool + head MLP
    k_pool_seg<<<(N_GRAPHS * 16) / 256, 256, 0, stream>>>();
    k_head1<<<(N_GRAPHS * 64) / 256, 256, 0, stream>>>(Wc1, bc1);
    k_head2<<<(N_GRAPHS + 255) / 256, 256, 0, stream>>>(Wc2, bc2, outp);
}